// Round 1
// baseline (3150.348 us; speedup 1.0000x reference)
//
#include <hip/hip_runtime.h>

// LiquidNN LTC: B=512, S=512, D=H=128, O=1, UNFOLDS=6, dt=0.1, tau=1.
// ONE WAVE PER BATCH ROW (grid=512, block=64, 2 waves/CU).
// Lane owns outputs o0=2*lane, o0+1: full 128-MAC dot products per output,
// so no cross-lane reduce and -- critically -- no __syncthreads anywhere:
// all h exchange is intra-wave via LDS (DS ops of one wave complete in order).
// W_r AND W_in rows register-resident as f16 pairs (~256 VGPRs of weights;
// occupancy is problem-capped at 2 waves/CU, so registers are free).
// h broadcast: all lanes read the same 16 ds_read_b128 addresses (broadcast,
// no bank traffic amplification). h fp32 in registers (authoritative).

typedef _Float16 v2h __attribute__((ext_vector_type(2)));

#define S_LEN 512
#define HDIM  128
#define NUNF  6
#define DTC   0.1f

__device__ __forceinline__ float fast_tanh(float y) {
    // tanh(y) = 1 - 2/(e^{2y}+1); v_exp/v_rcp based, NaN-free at +-inf
    float u = __expf(2.0f * y);
    return 1.0f - __fdividef(2.0f, u + 1.0f);
}

// Two 128-length f16 dot products (weights WA, WB in regs) against a
// wave-uniform LDS vector at BASE (16 broadcast ds_read_b128).
// 8 independent accumulator chains of 16 dot2 each -> dep latency hidden.
#define MATVEC128(WA, WB, BASE, R0, R1) do {                                   \
    const float4* _hp = reinterpret_cast<const float4*>(BASE);                 \
    float4 _hv[16];                                                            \
    _Pragma("unroll")                                                          \
    for (int _j = 0; _j < 16; ++_j) _hv[_j] = _hp[_j];                         \
    const v2h* _hh = reinterpret_cast<const v2h*>(_hv);                        \
    float _a0=0.f,_a1=0.f,_a2=0.f,_a3=0.f;                                     \
    float _b0=0.f,_b1=0.f,_b2=0.f,_b3=0.f;                                     \
    _Pragma("unroll")                                                          \
    for (int _j = 0; _j < 64; _j += 4) {                                       \
        _a0 = __builtin_amdgcn_fdot2(WA[_j],   _hh[_j],   _a0, false);         \
        _a1 = __builtin_amdgcn_fdot2(WA[_j+1], _hh[_j+1], _a1, false);         \
        _a2 = __builtin_amdgcn_fdot2(WA[_j+2], _hh[_j+2], _a2, false);         \
        _a3 = __builtin_amdgcn_fdot2(WA[_j+3], _hh[_j+3], _a3, false);         \
        _b0 = __builtin_amdgcn_fdot2(WB[_j],   _hh[_j],   _b0, false);         \
        _b1 = __builtin_amdgcn_fdot2(WB[_j+1], _hh[_j+1], _b1, false);         \
        _b2 = __builtin_amdgcn_fdot2(WB[_j+2], _hh[_j+2], _b2, false);         \
        _b3 = __builtin_amdgcn_fdot2(WB[_j+3], _hh[_j+3], _b3, false);         \
    }                                                                          \
    R0 = (_a0 + _a1) + (_a2 + _a3);                                            \
    R1 = (_b0 + _b1) + (_b2 + _b3);                                            \
} while (0)

__global__ __launch_bounds__(64, 1)
void ltc_kernel(const float* __restrict__ x,
                const float* __restrict__ W_in,
                const float* __restrict__ b_in,
                const float* __restrict__ W_r,
                const float* __restrict__ b_r,
                const float* __restrict__ W_fc,
                const float* __restrict__ b_fc,
                float* __restrict__ out)
{
    const int b    = blockIdx.x;
    const int lane = threadIdx.x;    // 0..63 (one wave)
    const int o0   = lane << 1;      // outputs o0, o0+1

    __shared__ __align__(16) _Float16 hbuf[2][HDIM];
    __shared__ __align__(16) _Float16 xbuf[2][HDIM];

    // ---- one-time: 2 W_r rows + 2 W_in rows into registers as f16 pairs ----
    v2h wr0[64], wr1[64], wi0[64], wi1[64];
    {
        const float4* p0 = reinterpret_cast<const float4*>(W_r  + (size_t)o0 * HDIM);
        const float4* p1 = reinterpret_cast<const float4*>(W_r  + (size_t)(o0 + 1) * HDIM);
        const float4* q0 = reinterpret_cast<const float4*>(W_in + (size_t)o0 * HDIM);
        const float4* q1 = reinterpret_cast<const float4*>(W_in + (size_t)(o0 + 1) * HDIM);
#pragma unroll
        for (int j = 0; j < 32; ++j) {
            float4 f;
            f = p0[j];
            wr0[2*j]   = v2h{(_Float16)f.x, (_Float16)f.y};
            wr0[2*j+1] = v2h{(_Float16)f.z, (_Float16)f.w};
            f = p1[j];
            wr1[2*j]   = v2h{(_Float16)f.x, (_Float16)f.y};
            wr1[2*j+1] = v2h{(_Float16)f.z, (_Float16)f.w};
            f = q0[j];
            wi0[2*j]   = v2h{(_Float16)f.x, (_Float16)f.y};
            wi0[2*j+1] = v2h{(_Float16)f.z, (_Float16)f.w};
            f = q1[j];
            wi1[2*j]   = v2h{(_Float16)f.x, (_Float16)f.y};
            wi1[2*j+1] = v2h{(_Float16)f.z, (_Float16)f.w};
        }
    }
    const float2 biv = *reinterpret_cast<const float2*>(b_in + o0);
    const float2 brv = *reinterpret_cast<const float2*>(b_r  + o0);

    const float* x_row = x + (size_t)b * S_LEN * HDIM;

    // ---- prologue: h = 0, stage x[0] as f16 (no barrier: single wave) ----
    {
        float2 x0 = *reinterpret_cast<const float2*>(x_row + o0);
        *reinterpret_cast<v2h*>(&xbuf[0][o0]) = v2h{(_Float16)x0.x, (_Float16)x0.y};
        *reinterpret_cast<v2h*>(&hbuf[0][o0]) = v2h{(_Float16)0.f, (_Float16)0.f};
    }

    float h0 = 0.0f, h1 = 0.0f;   // fp32 authoritative h (lane-local outputs)

#pragma unroll 1
    for (int s = 0; s < S_LEN; ++s) {
        // prefetch next step's x (coalesced 8 B/lane; latency hidden by step)
        float2 xn = make_float2(0.0f, 0.0f);
        if (s + 1 < S_LEN)
            xn = *reinterpret_cast<const float2*>(x_row + (size_t)(s + 1) * HDIM + o0);

        // ---- input map: also covers the prev h-write -> h-read LDS latency ----
        float xs0, xs1;
        MATVEC128(wi0, wi1, &xbuf[s & 1][0], xs0, xs1);
        const float xin0 = xs0 + biv.x;
        const float xin1 = xs1 + biv.y;

        // ---- 6 ODE unfolds, intra-wave only ----
#pragma unroll
        for (int u = 0; u < NUNF; ++u) {
            float s0, s1;
            MATVEC128(wr0, wr1, &hbuf[u & 1][0], s0, s1);
            if (u == 0)  // stage next x mid-step (global load has landed by now)
                *reinterpret_cast<v2h*>(&xbuf[(s + 1) & 1][o0]) =
                    v2h{(_Float16)xn.x, (_Float16)xn.y};
            float v0 = fast_tanh(xin0 + brv.x + s0);
            float v1 = fast_tanh(xin1 + brv.y + s1);
            h0 += DTC * (v0 - h0);   // tau=1: h += dt*(-h+v)
            h1 += DTC * (v1 - h1);
            *reinterpret_cast<v2h*>(&hbuf[(u + 1) & 1][o0]) =
                v2h{(_Float16)h0, (_Float16)h1};
        }
    }

    // ---- epilogue: out[b] = h . W_fc[0,:] + b_fc (wave-wide shuffle reduce) ----
    const float2 wfc = *reinterpret_cast<const float2*>(W_fc + o0);
    float partial = h0 * wfc.x + h1 * wfc.y;
#pragma unroll
    for (int d = 1; d < 64; d <<= 1) partial += __shfl_xor(partial, d);
    if (lane == 0) out[b] = partial + b_fc[0];
}

extern "C" void kernel_launch(void* const* d_in, const int* in_sizes, int n_in,
                              void* d_out, int out_size, void* d_ws, size_t ws_size,
                              hipStream_t stream) {
    const float* x    = (const float*)d_in[0];
    const float* W_in = (const float*)d_in[1];
    const float* b_in = (const float*)d_in[2];
    const float* W_r  = (const float*)d_in[3];
    const float* b_r  = (const float*)d_in[4];
    const float* W_fc = (const float*)d_in[5];
    const float* b_fc = (const float*)d_in[6];
    float* outp = (float*)d_out;
    (void)in_sizes; (void)n_in; (void)out_size; (void)d_ws; (void)ws_size;
    ltc_kernel<<<dim3(512), dim3(64), 0, stream>>>(x, W_in, b_in, W_r, b_r, W_fc, b_fc, outp);
}

// Round 2
// 1786.140 us; speedup vs baseline: 1.7638x; 1.7638x over previous
//
#include <hip/hip_runtime.h>

// LiquidNN LTC: B=512, S=512, D=H=128, O=1, UNFOLDS=6, dt=0.1, tau=1.
// 2 waves per batch row (grid=512, block=128, 2 blocks/CU).
// Thread t owns output row o=t: FULL 128-MAC dot product per output, so
// NO cross-lane shuffle in the main loop (round-0 paid ~120cyc ds_swizzle
// latency per phase). W_in/W_r rows live in NAMED ext_vector_type(16)
// registers (no arrays -> no alloca -> PromoteAlloca cannot spill them;
// round-1's 1KB of private arrays fell to scratch, VGPR=148, 2x slower).
// h fp32 in registers (authoritative), f16 copy double-buffered in LDS;
// all lanes read the SAME LDS addresses (broadcast, no bank traffic).

typedef _Float16 v2h    __attribute__((ext_vector_type(2)));
typedef _Float16 v16h   __attribute__((ext_vector_type(16)));
typedef float    f32x16 __attribute__((ext_vector_type(16)));

#define S_LEN 512
#define HDIM  128
#define NUNF  6
#define DTC   0.1f

__device__ __forceinline__ float fast_tanh(float y) {
    // tanh(y) = 1 - 2/(e^{2y}+1); v_exp/v_rcp based, NaN-free at +-inf
    float u = __expf(2.0f * y);
    return 1.0f - __fdividef(2.0f, u + 1.0f);
}

// 16 MACs: one v16h weight chunk vs one v16h vector chunk, 4 acc chains.
#define DOT16(W, X)                                                \
    a0 = __builtin_amdgcn_fdot2(W.s01, X.s01, a0, false);          \
    a1 = __builtin_amdgcn_fdot2(W.s23, X.s23, a1, false);          \
    a2 = __builtin_amdgcn_fdot2(W.s45, X.s45, a2, false);          \
    a3 = __builtin_amdgcn_fdot2(W.s67, X.s67, a3, false);          \
    a0 = __builtin_amdgcn_fdot2(W.s89, X.s89, a0, false);          \
    a1 = __builtin_amdgcn_fdot2(W.sab, X.sab, a1, false);          \
    a2 = __builtin_amdgcn_fdot2(W.scd, X.scd, a2, false);          \
    a3 = __builtin_amdgcn_fdot2(W.sef, X.sef, a3, false);

// Full 128-length f16 dot: named weight regs W##0..W##7 vs LDS vector at BUF
// (16 broadcast ds_read_b128 -> 8 v16h temps).
#define MATVEC(W, BUF, RES) do {                                   \
    const v16h* _p = reinterpret_cast<const v16h*>(BUF);           \
    v16h x0 = _p[0], x1 = _p[1], x2 = _p[2], x3 = _p[3];           \
    v16h x4 = _p[4], x5 = _p[5], x6 = _p[6], x7 = _p[7];           \
    float a0 = 0.f, a1 = 0.f, a2 = 0.f, a3 = 0.f;                  \
    DOT16(W##0, x0) DOT16(W##1, x1) DOT16(W##2, x2) DOT16(W##3, x3)\
    DOT16(W##4, x4) DOT16(W##5, x5) DOT16(W##6, x6) DOT16(W##7, x7)\
    RES = (a0 + a1) + (a2 + a3);                                   \
} while (0)

__global__ __launch_bounds__(128, 1)
void ltc_kernel(const float* __restrict__ x,
                const float* __restrict__ W_in,
                const float* __restrict__ b_in,
                const float* __restrict__ W_r,
                const float* __restrict__ b_r,
                const float* __restrict__ W_fc,
                const float* __restrict__ b_fc,
                float* __restrict__ out)
{
    const int b   = blockIdx.x;
    const int tid = threadIdx.x;     // 0..127 == output row o

    __shared__ __align__(16) _Float16 hbuf[2][HDIM];
    __shared__ __align__(16) _Float16 xbuf[2][HDIM];
    __shared__ float red[2];

    // ---- one-time: own W_r row + W_in row -> 16 named v16h regs (128 VGPRs) ----
    const f32x16* wrp = reinterpret_cast<const f32x16*>(W_r  + (size_t)tid * HDIM);
    const f32x16* wip = reinterpret_cast<const f32x16*>(W_in + (size_t)tid * HDIM);
    v16h wr0 = __builtin_convertvector(wrp[0], v16h);
    v16h wr1 = __builtin_convertvector(wrp[1], v16h);
    v16h wr2 = __builtin_convertvector(wrp[2], v16h);
    v16h wr3 = __builtin_convertvector(wrp[3], v16h);
    v16h wr4 = __builtin_convertvector(wrp[4], v16h);
    v16h wr5 = __builtin_convertvector(wrp[5], v16h);
    v16h wr6 = __builtin_convertvector(wrp[6], v16h);
    v16h wr7 = __builtin_convertvector(wrp[7], v16h);
    v16h wi0 = __builtin_convertvector(wip[0], v16h);
    v16h wi1 = __builtin_convertvector(wip[1], v16h);
    v16h wi2 = __builtin_convertvector(wip[2], v16h);
    v16h wi3 = __builtin_convertvector(wip[3], v16h);
    v16h wi4 = __builtin_convertvector(wip[4], v16h);
    v16h wi5 = __builtin_convertvector(wip[5], v16h);
    v16h wi6 = __builtin_convertvector(wip[6], v16h);
    v16h wi7 = __builtin_convertvector(wip[7], v16h);

    const float binv = b_in[tid];
    const float brv  = b_r[tid];

    const float* x_row = x + (size_t)b * S_LEN * HDIM;

    // ---- prologue: h = 0, stage x[0] as f16 ----
    xbuf[0][tid] = (_Float16)x_row[tid];
    hbuf[0][tid] = (_Float16)0.0f;
    __syncthreads();

    float h = 0.0f;   // fp32 authoritative h (thread-local output)

#pragma unroll 1
    for (int s = 0; s < S_LEN; ++s) {
        // prefetch next step's x (coalesced 4B/lane; latency hidden by step)
        float xn = 0.0f;
        if (s + 1 < S_LEN)
            xn = x_row[(size_t)(s + 1) * HDIM + tid];

        // ---- input map: independent of h -> covers prev h-write->read latency ----
        float xs;
        MATVEC(wi, &xbuf[s & 1][0], xs);
        const float xin = xs + binv;

        // ---- 6 ODE unfolds ----
#pragma unroll
        for (int u = 0; u < NUNF; ++u) {
            float sr;
            MATVEC(wr, &hbuf[u & 1][0], sr);
            float v = fast_tanh(xin + brv + sr);
            h += DTC * (v - h);                    // tau=1: h += dt*(-h+v)
            hbuf[(u + 1) & 1][tid] = (_Float16)h;
            if (u == 0)  // stage next x mid-step (global load landed by now)
                xbuf[(s + 1) & 1][tid] = (_Float16)xn;
            __syncthreads();
        }
    }

    // ---- epilogue: out[b] = h . W_fc[0,:] + b_fc ----
    float partial = h * W_fc[tid];
#pragma unroll
    for (int d = 1; d < 64; d <<= 1) partial += __shfl_xor(partial, d);
    if ((tid & 63) == 0) red[tid >> 6] = partial;
    __syncthreads();
    if (tid == 0) out[b] = red[0] + red[1] + b_fc[0];
}

extern "C" void kernel_launch(void* const* d_in, const int* in_sizes, int n_in,
                              void* d_out, int out_size, void* d_ws, size_t ws_size,
                              hipStream_t stream) {
    const float* x    = (const float*)d_in[0];
    const float* W_in = (const float*)d_in[1];
    const float* b_in = (const float*)d_in[2];
    const float* W_r  = (const float*)d_in[3];
    const float* b_r  = (const float*)d_in[4];
    const float* W_fc = (const float*)d_in[5];
    const float* b_fc = (const float*)d_in[6];
    float* outp = (float*)d_out;
    (void)in_sizes; (void)n_in; (void)out_size; (void)d_ws; (void)ws_size;
    ltc_kernel<<<dim3(512), dim3(128), 0, stream>>>(x, W_in, b_in, W_r, b_r, W_fc, b_fc, outp);
}